// Round 2
// baseline (2694.387 us; speedup 1.0000x reference)
//
#include <hip/hip_runtime.h>
#include <hip/hip_bf16.h>

typedef float f32x4 __attribute__((ext_vector_type(4)));
typedef unsigned short u16x4 __attribute__((ext_vector_type(4)));
typedef unsigned short u16x8 __attribute__((ext_vector_type(8)));
typedef short s16x8 __attribute__((ext_vector_type(8)));   // MFMA A/B fragment (8 bf16)

#define NN 200000
#define NE 400000
#define NG 4096

__device__ __forceinline__ unsigned short f2bf(float f) {
    union { float f; unsigned int u; } v; v.f = f;
    unsigned int r = v.u + 0x7FFF + ((v.u >> 16) & 1);   // RNE
    return (unsigned short)(r >> 16);
}
__device__ __forceinline__ float bf2f(unsigned short b) {
    union { unsigned int u; float f; } v; v.u = ((unsigned int)b) << 16;
    return v.f;
}

// ---- int64-vs-int32 index detection: int64 little-endian -> odd int32 words all 0 ----
__global__ void detect_i64(const int* __restrict__ ei, int* __restrict__ flag) {
    unsigned long long m = __ballot(ei[threadIdx.x * 2 + 1] == 0);
    if (threadIdx.x == 0) *flag = (~m == 0ULL) ? 1 : 0;
}

__device__ __forceinline__ int load_idx(const int* p, long long i, int f64) {
    return f64 ? (int)((const long long*)p)[i] : p[i];
}

// ---------------- weight convert+transpose: Wt[n][k] = bf16(W[k][n]) ----------------
__global__ void wt_conv(const float* __restrict__ W, unsigned short* __restrict__ Wt,
                        int K, int N) {
    int tid = blockIdx.x * 256 + threadIdx.x;
    if (tid >= K * N) return;
    int n = tid / K, k = tid - n * K;
    Wt[tid] = f2bf(W[(size_t)k * N + n]);
}

// ------- fused edge projection + message relu + scatter-add (atomics) -------
// accum[dst] += relu(x[src] + ea @ We + be)
template<int D, typename XT>
__global__ __launch_bounds__(256)
void msg_scatter(const XT* __restrict__ x, const float* __restrict__ ea,
                 const float* __restrict__ We, const float* __restrict__ be,
                 const int* __restrict__ ei, const int* __restrict__ flag,
                 float* __restrict__ accum) {
    constexpr int TPE = D / 4;
    int tid = blockIdx.x * 256 + threadIdx.x;
    int e = tid / TPE;
    if (e >= NE) return;
    const int f64 = *flag;
    int f = (tid % TPE) * 4;
    int s = load_idx(ei, e, f64);
    int d = load_idx(ei, (long long)NE + e, f64);
    if ((unsigned)s >= NN || (unsigned)d >= NN) return;   // never faults
    f32x4 acc = *(const f32x4*)(be + f);
    const float* eap = ea + (size_t)e * 16;
#pragma unroll
    for (int k = 0; k < 16; ++k) {
        float a = eap[k];
        f32x4 w = *(const f32x4*)(We + k * D + f);
        acc += w * a;
    }
    f32x4 xv;
    if constexpr (sizeof(XT) == 4) {
        xv = *(const f32x4*)((const float*)x + (size_t)s * D + f);
    } else {
        u16x4 hv = *(const u16x4*)((const unsigned short*)x + (size_t)s * D + f);
        xv.x = bf2f(hv.x); xv.y = bf2f(hv.y); xv.z = bf2f(hv.z); xv.w = bf2f(hv.w);
    }
    float* outp = accum + (size_t)d * D + f;
#pragma unroll
    for (int i = 0; i < 4; ++i) {
        float m = acc[i] + xv[i];
        if (m > 0.f) unsafeAtomicAdd(outp + i, m);        // relu: skip zeros
    }
}

// ------- bf16 MFMA GEMM: C[M,256] = relu((A1(+A2)) @ W + bias) -------
// tile 64x64, BK=64, 4 waves, mfma_f32_16x16x32_bf16
// AT: float (f32 act) or unsigned short (bf16 act). CT: unsigned short or float.
template<int K, typename AT, bool HASA2, typename CT>
__global__ __launch_bounds__(256)
void gemm_bias_relu(const AT* __restrict__ A1, const float* __restrict__ A2,
                    const unsigned short* __restrict__ Wt, const float* __restrict__ bias,
                    CT* __restrict__ C) {
    constexpr int LDT = 72;                  // padded bf16 row
    __shared__ unsigned short As[64 * LDT];
    __shared__ unsigned short Bs[64 * LDT];
    const int n0 = blockIdx.x * 64;
    const int m0 = blockIdx.y * 64;
    const int tid = threadIdx.x;
    const int wave = tid >> 6;
    const int lane = tid & 63;
    const int lm = lane & 15;
    const int lq = lane >> 4;

    f32x4 acc[4] = {};

    for (int k0 = 0; k0 < K; k0 += 64) {
        // ---- stage A ----
        if constexpr (sizeof(AT) == 4) {
#pragma unroll
            for (int i = 0; i < 4; ++i) {
                int r = (tid >> 4) + i * 16;
                int c = (tid & 15) * 4;
                f32x4 v = *(const f32x4*)((const float*)A1 + (size_t)(m0 + r) * K + (k0 + c));
                if constexpr (HASA2)
                    v += *(const f32x4*)(A2 + (size_t)(m0 + r) * K + (k0 + c));
                u16x4 b;
                b.x = f2bf(v.x); b.y = f2bf(v.y); b.z = f2bf(v.z); b.w = f2bf(v.w);
                *(u16x4*)(As + r * LDT + c) = b;
            }
        } else {
#pragma unroll
            for (int i = 0; i < 2; ++i) {
                int r = (tid >> 3) + i * 32;
                int c = (tid & 7) * 8;
                u16x8 hv = *(const u16x8*)((const unsigned short*)A1 + (size_t)(m0 + r) * K + (k0 + c));
                if constexpr (HASA2) {
                    const float* ap = A2 + (size_t)(m0 + r) * K + (k0 + c);
                    f32x4 a0 = *(const f32x4*)ap;
                    f32x4 a1 = *(const f32x4*)(ap + 4);
                    u16x8 o;
                    o[0] = f2bf(bf2f(hv[0]) + a0.x); o[1] = f2bf(bf2f(hv[1]) + a0.y);
                    o[2] = f2bf(bf2f(hv[2]) + a0.z); o[3] = f2bf(bf2f(hv[3]) + a0.w);
                    o[4] = f2bf(bf2f(hv[4]) + a1.x); o[5] = f2bf(bf2f(hv[5]) + a1.y);
                    o[6] = f2bf(bf2f(hv[6]) + a1.z); o[7] = f2bf(bf2f(hv[7]) + a1.w);
                    *(u16x8*)(As + r * LDT + c) = o;
                } else {
                    *(u16x8*)(As + r * LDT + c) = hv;
                }
            }
        }
        // ---- stage B from Wt[n][k] (already bf16) ----
#pragma unroll
        for (int i = 0; i < 2; ++i) {
            int n = (tid >> 3) + i * 32;
            int c = (tid & 7) * 8;
            u16x8 v = *(const u16x8*)(Wt + (size_t)(n0 + n) * K + (k0 + c));
            *(u16x8*)(Bs + n * LDT + c) = v;
        }
        __syncthreads();
#pragma unroll
        for (int j = 0; j < 64; j += 32) {
            s16x8 a = *(const s16x8*)(As + (wave * 16 + lm) * LDT + j + lq * 8);
#pragma unroll
            for (int t = 0; t < 4; ++t) {
                s16x8 b = *(const s16x8*)(Bs + (t * 16 + lm) * LDT + j + lq * 8);
                acc[t] = __builtin_amdgcn_mfma_f32_16x16x32_bf16(a, b, acc[t], 0, 0, 0);
            }
        }
        __syncthreads();
    }
    // epilogue: C/D layout col=lane&15, row=(lane>>4)*4+reg
    const int row = m0 + wave * 16 + lq * 4;
#pragma unroll
    for (int t = 0; t < 4; ++t) {
        int col = n0 + t * 16 + lm;
        float bv = bias[col];
#pragma unroll
        for (int r = 0; r < 4; ++r) {
            float v = fmaxf(acc[t][r] + bv, 0.f);
            if constexpr (sizeof(CT) == 2)
                C[(size_t)(row + r) * 256 + col] = (CT)f2bf(v);
            else
                C[(size_t)(row + r) * 256 + col] = (CT)v;
        }
    }
}

// ------- mean pool: batch sorted -> binary search + segment sum, no atomics -------
__global__ __launch_bounds__(256)
void pool_mean(const float* __restrict__ h, const int* __restrict__ batch,
               const int* __restrict__ flag, float* __restrict__ out) {
    const int f64 = *flag;
    int g = blockIdx.x;
    int a = 0, b = NN;
    while (a < b) { int m = (a + b) >> 1; int v = load_idx(batch, m, f64); if (v < g) a = m + 1; else b = m; }
    int lo = a;
    b = NN;
    while (a < b) { int m = (a + b) >> 1; int v = load_idx(batch, m, f64); if (v < g + 1) a = m + 1; else b = m; }
    int hi = a;
    int f = threadIdx.x;
    float s = 0.f;
    for (int n = lo; n < hi; ++n) s += h[(size_t)n * 256 + f];
    float cnt = (float)(hi - lo);
    out[(size_t)g * 256 + f] = s / fmaxf(cnt, 1.f);
}

extern "C" void kernel_launch(void* const* d_in, const int* in_sizes, int n_in,
                              void* d_out, int out_size, void* d_ws, size_t ws_size,
                              hipStream_t stream) {
    const float* x   = (const float*)d_in[0];
    const float* ea  = (const float*)d_in[1];
    const float* We1 = (const float*)d_in[2];
    const float* be1 = (const float*)d_in[3];
    const float* W1a = (const float*)d_in[4];
    const float* b1a = (const float*)d_in[5];
    const float* W1b = (const float*)d_in[6];
    const float* b1b = (const float*)d_in[7];
    const float* We2 = (const float*)d_in[8];
    const float* be2 = (const float*)d_in[9];
    const float* W2a = (const float*)d_in[10];
    const float* b2a = (const float*)d_in[11];
    const float* W2b = (const float*)d_in[12];
    const float* b2b = (const float*)d_in[13];
    const int*   ei  = (const int*)d_in[14];
    const int*   bat = (const int*)d_in[15];
    float* out = (float*)d_out;

    // workspace layout: 204.8 MB f32 (aggr / final h) + 2x 102.4 MB bf16 + weights + flag
    char* ws = (char*)d_ws;
    const size_t SZF = (size_t)NN * 256 * 4;
    const size_t SZH = (size_t)NN * 256 * 2;
    float*          bufF = (float*)ws;                          // aggr1/aggr2, then h2b f32
    unsigned short* bufH1 = (unsigned short*)(ws + SZF);        // h1, then h2a
    unsigned short* bufH2 = (unsigned short*)(ws + SZF + SZH);  // h1o
    unsigned short* Wt1a = (unsigned short*)(ws + SZF + 2 * SZH);
    unsigned short* Wt1b = Wt1a + 128 * 256;
    unsigned short* Wt2a = Wt1b + 256 * 256;
    unsigned short* Wt2b = Wt2a + 256 * 256;
    int* flag = (int*)(Wt2b + 256 * 256);
    // total ~410.06 MB

    detect_i64<<<1, 64, 0, stream>>>(ei, flag);
    wt_conv<<<(128 * 256 + 255) / 256, 256, 0, stream>>>(W1a, Wt1a, 128, 256);
    wt_conv<<<(256 * 256 + 255) / 256, 256, 0, stream>>>(W1b, Wt1b, 256, 256);
    wt_conv<<<(256 * 256 + 255) / 256, 256, 0, stream>>>(W2a, Wt2a, 256, 256);
    wt_conv<<<(256 * 256 + 255) / 256, 256, 0, stream>>>(W2b, Wt2b, 256, 256);

    dim3 gg(4, 3125);   // 200000/64 = 3125, 256/64 = 4

    // ---- layer 1 ----
    hipMemsetAsync(bufF, 0, (size_t)NN * 128 * 4, stream);
    msg_scatter<128, float><<<(NE * 32) / 256, 256, 0, stream>>>(x, ea, We1, be1, ei, flag, bufF);
    gemm_bias_relu<128, float, true, unsigned short><<<gg, 256, 0, stream>>>(x, bufF, Wt1a, b1a, bufH1);
    gemm_bias_relu<256, unsigned short, false, unsigned short><<<gg, 256, 0, stream>>>(bufH1, nullptr, Wt1b, b1b, bufH2);

    // ---- layer 2 ----
    hipMemsetAsync(bufF, 0, SZF, stream);
    msg_scatter<256, unsigned short><<<(NE * 64) / 256, 256, 0, stream>>>(bufH2, ea, We2, be2, ei, flag, bufF);
    gemm_bias_relu<256, unsigned short, true, unsigned short><<<gg, 256, 0, stream>>>(bufH2, bufF, Wt2a, b2a, bufH1);
    gemm_bias_relu<256, unsigned short, false, float><<<gg, 256, 0, stream>>>(bufH1, nullptr, Wt2b, b2b, bufF);

    // ---- mean pool ----
    pool_mean<<<NG, 256, 0, stream>>>(bufF, bat, flag, out);
}

// Round 4
// 1118.223 us; speedup vs baseline: 2.4095x; 2.4095x over previous
//
#include <hip/hip_runtime.h>
#include <hip/hip_bf16.h>

typedef float f32x4 __attribute__((ext_vector_type(4)));
typedef unsigned short u16x4 __attribute__((ext_vector_type(4)));
typedef unsigned short u16x8 __attribute__((ext_vector_type(8)));
typedef short s16x8 __attribute__((ext_vector_type(8)));   // MFMA A/B fragment (8 bf16)

#define NN 200000
#define NE 400000
#define NG 4096
#define SCHUNK 1024
#define NSCAN ((NN + SCHUNK - 1) / SCHUNK)   // 196

__device__ __forceinline__ unsigned short f2bf(float f) {
    union { float f; unsigned int u; } v; v.f = f;
    unsigned int r = v.u + 0x7FFF + ((v.u >> 16) & 1);   // RNE
    return (unsigned short)(r >> 16);
}
__device__ __forceinline__ float bf2f(unsigned short b) {
    union { unsigned int u; float f; } v; v.u = ((unsigned int)b) << 16;
    return v.f;
}

// ---- int64-vs-int32 index detection: int64 little-endian -> odd int32 words all 0 ----
__global__ void detect_i64(const int* __restrict__ ei, int* __restrict__ flag) {
    unsigned long long m = __ballot(ei[threadIdx.x * 2 + 1] == 0);
    if (threadIdx.x == 0) *flag = (~m == 0ULL) ? 1 : 0;
}
__device__ __forceinline__ int load_idx(const int* p, long long i, int f64) {
    return f64 ? (int)((const long long*)p)[i] : p[i];
}

// ---------------- weight convert+transpose: Wt[n][k] = bf16(W[k][n]) ----------------
__global__ void wt_conv(const float* __restrict__ W, unsigned short* __restrict__ Wt,
                        int K, int N) {
    int tid = blockIdx.x * 256 + threadIdx.x;
    if (tid >= K * N) return;
    int n = tid / K, k = tid - n * K;
    Wt[tid] = f2bf(W[(size_t)k * N + n]);
}

__global__ __launch_bounds__(256) void copy_int(const int* __restrict__ a,
                                                int* __restrict__ b, int n) {
    int i = blockIdx.x * 256 + threadIdx.x;
    if (i < n) b[i] = a[i];
}

// ---------------- CSR build: histogram -> scan -> fill ----------------
// hist and fill use IDENTICAL validity criterion (both endpoints) so every
// reserved slot is filled -> no poison reads downstream.
__global__ __launch_bounds__(256) void hist_dst(const int* __restrict__ ei,
                                                const int* __restrict__ flag,
                                                int* __restrict__ deg) {
    int e = blockIdx.x * 256 + threadIdx.x;
    if (e >= NE) return;
    int f64 = *flag;
    int s = load_idx(ei, e, f64);
    int d = load_idx(ei, (long long)NE + e, f64);
    if ((unsigned)s < NN && (unsigned)d < NN) atomicAdd(&deg[d], 1);
}

__global__ __launch_bounds__(256) void scan_bsum(const int* __restrict__ deg,
                                                 int* __restrict__ bsum) {
    __shared__ int red[256];
    int t = threadIdx.x, base = blockIdx.x * SCHUNK + t * 4;
    int s = 0;
#pragma unroll
    for (int c = 0; c < 4; ++c) { int i = base + c; if (i < NN) s += deg[i]; }
    red[t] = s; __syncthreads();
    for (int o = 128; o > 0; o >>= 1) { if (t < o) red[t] += red[t + o]; __syncthreads(); }
    if (t == 0) bsum[blockIdx.x] = red[0];
}

__global__ void scan_carry(int* __restrict__ bsum, int* __restrict__ rowptr_end) {
    if (threadIdx.x == 0) {
        int run = 0;
        for (int i = 0; i < NSCAN; ++i) { int v = bsum[i]; bsum[i] = run; run += v; }
        *rowptr_end = run;   // rowptr[NN]
    }
}

__global__ __launch_bounds__(256) void scan_final(const int* __restrict__ deg,
                                                  const int* __restrict__ bsum,
                                                  int* __restrict__ rowptr) {
    __shared__ int lds[256];
    int t = threadIdx.x, base = blockIdx.x * SCHUNK + t * 4;
    int v[4], s = 0;
#pragma unroll
    for (int c = 0; c < 4; ++c) { int i = base + c; v[c] = (i < NN) ? deg[i] : 0; s += v[c]; }
    lds[t] = s; __syncthreads();
    for (int o = 1; o < 256; o <<= 1) {
        int x = 0;
        if (t >= o) x = lds[t - o];
        __syncthreads();
        if (t >= o) lds[t] += x;
        __syncthreads();
    }
    int run = lds[t] - s + bsum[blockIdx.x];
#pragma unroll
    for (int c = 0; c < 4; ++c) { int i = base + c; if (i < NN) rowptr[i] = run; run += v[c]; }
}

__global__ __launch_bounds__(256) void fill_csr(const int* __restrict__ ei,
                                                const int* __restrict__ flag,
                                                int* __restrict__ cursor,
                                                int* __restrict__ srcs,
                                                int* __restrict__ eidx) {
    int e = blockIdx.x * 256 + threadIdx.x;
    if (e >= NE) return;
    int f64 = *flag;
    int s = load_idx(ei, e, f64);
    int d = load_idx(ei, (long long)NE + e, f64);
    if ((unsigned)s >= NN || (unsigned)d >= NN) return;
    int pos = atomicAdd(&cursor[d], 1);
    if ((unsigned)pos < NE) { srcs[pos] = s; eidx[pos] = e; }
}

// ---------------- gather-aggregate: out[i] = bf16( x_i + sum_e relu(x[src]+ea[e]@We+be) ) ----------------
// one wave per node, We column-slice in registers, no atomics
template<int D, typename XT>
__global__ __launch_bounds__(256)
void gather_aggr(const XT* __restrict__ x, const float* __restrict__ ea,
                 const float* __restrict__ We, const float* __restrict__ be,
                 const int* __restrict__ rowptr, const int* __restrict__ srcs,
                 const int* __restrict__ eidx, unsigned short* __restrict__ out) {
    constexpr int C = D / 64;                 // floats per lane
    const int wave = threadIdx.x >> 6;
    const int lane = threadIdx.x & 63;
    const int node = blockIdx.x * 4 + wave;   // NN divisible by 4
    const int f = lane * C;

    float wr[16][C], ber[C];
#pragma unroll
    for (int k = 0; k < 16; ++k)
#pragma unroll
        for (int c = 0; c < C; ++c) wr[k][c] = We[k * D + f + c];
#pragma unroll
    for (int c = 0; c < C; ++c) ber[c] = be[f + c];

    float acc[C];
    if constexpr (sizeof(XT) == 4) {
        const float* xp = (const float*)x + (size_t)node * D + f;
#pragma unroll
        for (int c = 0; c < C; ++c) acc[c] = xp[c];
    } else {
        const unsigned short* xp = (const unsigned short*)x + (size_t)node * D + f;
#pragma unroll
        for (int c = 0; c < C; ++c) acc[c] = bf2f(xp[c]);
    }

    int j = rowptr[node], end = rowptr[node + 1];
    if (j > end || (unsigned)end > NE) { j = 0; end = 0; }   // paranoia: never fault
    for (; j < end; ++j) {
        int s = srcs[j], e = eidx[j];
        if ((unsigned)s >= NN || (unsigned)e >= NE) continue;
        const float* eap = ea + (size_t)e * 16;
        f32x4 e0 = *(const f32x4*)eap;
        f32x4 e1 = *(const f32x4*)(eap + 4);
        f32x4 e2 = *(const f32x4*)(eap + 8);
        f32x4 e3 = *(const f32x4*)(eap + 12);
        float m[C];
#pragma unroll
        for (int c = 0; c < C; ++c) m[c] = ber[c];
#pragma unroll
        for (int k = 0; k < 4; ++k)
#pragma unroll
            for (int c = 0; c < C; ++c) {
                m[c] += e0[k] * wr[k][c];
                m[c] += e1[k] * wr[4 + k][c];
                m[c] += e2[k] * wr[8 + k][c];
                m[c] += e3[k] * wr[12 + k][c];
            }
        if constexpr (sizeof(XT) == 4) {
            const float* xs = (const float*)x + (size_t)s * D + f;
#pragma unroll
            for (int c = 0; c < C; ++c) m[c] += xs[c];
        } else {
            u16x4 hv = *(const u16x4*)((const unsigned short*)x + (size_t)s * D + f);
#pragma unroll
            for (int c = 0; c < C; ++c) m[c] += bf2f(hv[c]);
        }
#pragma unroll
        for (int c = 0; c < C; ++c) acc[c] += fmaxf(m[c], 0.f);
    }

    unsigned short o[C];
#pragma unroll
    for (int c = 0; c < C; ++c) o[c] = f2bf(acc[c]);
    unsigned short* op = out + (size_t)node * D + f;
    if constexpr (C == 4) *(u16x4*)op = *(const u16x4*)o;
    else { op[0] = o[0]; op[1] = o[1]; }
}

// ------- bf16 MFMA GEMM: C[M,256] = relu(A @ W + bias), A bf16 [M,K], Wt bf16 [n][k] -------
// tile 64x64, BK=64, 4 waves, mfma_f32_16x16x32_bf16
template<int K, typename CT>
__global__ __launch_bounds__(256)
void gemm_bias_relu(const unsigned short* __restrict__ A,
                    const unsigned short* __restrict__ Wt, const float* __restrict__ bias,
                    CT* __restrict__ C) {
    constexpr int LDT = 72;                  // padded bf16 row
    __shared__ unsigned short As[64 * LDT];
    __shared__ unsigned short Bs[64 * LDT];
    const int n0 = blockIdx.x * 64;
    const int m0 = blockIdx.y * 64;
    const int tid = threadIdx.x;
    const int wave = tid >> 6;
    const int lane = tid & 63;
    const int lm = lane & 15;
    const int lq = lane >> 4;

    f32x4 acc[4] = {};

    for (int k0 = 0; k0 < K; k0 += 64) {
#pragma unroll
        for (int i = 0; i < 2; ++i) {
            int r = (tid >> 3) + i * 32;
            int c = (tid & 7) * 8;
            *(u16x8*)(As + r * LDT + c) =
                *(const u16x8*)(A + (size_t)(m0 + r) * K + (k0 + c));
            *(u16x8*)(Bs + r * LDT + c) =
                *(const u16x8*)(Wt + (size_t)(n0 + r) * K + (k0 + c));
        }
        __syncthreads();
#pragma unroll
        for (int j = 0; j < 64; j += 32) {
            s16x8 a = *(const s16x8*)(As + (wave * 16 + lm) * LDT + j + lq * 8);
#pragma unroll
            for (int t = 0; t < 4; ++t) {
                s16x8 b = *(const s16x8*)(Bs + (t * 16 + lm) * LDT + j + lq * 8);
                acc[t] = __builtin_amdgcn_mfma_f32_16x16x32_bf16(a, b, acc[t], 0, 0, 0);
            }
        }
        __syncthreads();
    }
    // epilogue: C/D layout col=lane&15, row=(lane>>4)*4+reg
    const int row = m0 + wave * 16 + lq * 4;
#pragma unroll
    for (int t = 0; t < 4; ++t) {
        int col = n0 + t * 16 + lm;
        float bv = bias[col];
#pragma unroll
        for (int r = 0; r < 4; ++r) {
            float v = fmaxf(acc[t][r] + bv, 0.f);
            if constexpr (sizeof(CT) == 2)
                C[(size_t)(row + r) * 256 + col] = (CT)f2bf(v);
            else
                C[(size_t)(row + r) * 256 + col] = (CT)v;
        }
    }
}

// ------- mean pool: batch sorted -> binary search + segment sum, no atomics -------
__global__ __launch_bounds__(256)
void pool_mean(const float* __restrict__ h, const int* __restrict__ batch,
               const int* __restrict__ flag, float* __restrict__ out) {
    const int f64 = *flag;
    int g = blockIdx.x;
    int a = 0, b = NN;
    while (a < b) { int m = (a + b) >> 1; if (load_idx(batch, m, f64) < g) a = m + 1; else b = m; }
    int lo = a;
    b = NN;
    while (a < b) { int m = (a + b) >> 1; if (load_idx(batch, m, f64) < g + 1) a = m + 1; else b = m; }
    int hi = a;
    int f = threadIdx.x;
    float s = 0.f;
    for (int n = lo; n < hi; ++n) s += h[(size_t)n * 256 + f];
    float cnt = (float)(hi - lo);
    out[(size_t)g * 256 + f] = s / fmaxf(cnt, 1.f);
}

extern "C" void kernel_launch(void* const* d_in, const int* in_sizes, int n_in,
                              void* d_out, int out_size, void* d_ws, size_t ws_size,
                              hipStream_t stream) {
    const float* x   = (const float*)d_in[0];
    const float* ea  = (const float*)d_in[1];
    const float* We1 = (const float*)d_in[2];
    const float* be1 = (const float*)d_in[3];
    const float* W1a = (const float*)d_in[4];
    const float* b1a = (const float*)d_in[5];
    const float* W1b = (const float*)d_in[6];
    const float* b1b = (const float*)d_in[7];
    const float* We2 = (const float*)d_in[8];
    const float* be2 = (const float*)d_in[9];
    const float* W2a = (const float*)d_in[10];
    const float* b2a = (const float*)d_in[11];
    const float* W2b = (const float*)d_in[12];
    const float* b2b = (const float*)d_in[13];
    const int*   ei  = (const int*)d_in[14];
    const int*   bat = (const int*)d_in[15];
    float* out = (float*)d_out;

    // ---- workspace layout: EXACT round-2-proven footprint (410,058,756 B) ----
    // R0 [204.8 MB f32]: first half = h1o bf16; CSR lives in second half
    //   (dead before GEMM4 overwrites all of R0 with final f32 h2b)
    // R1, R2 [102.4 MB bf16 each]; weights + flag after R2 (round-2 offsets).
    char* ws = (char*)d_ws;
    const size_t SZF = (size_t)NN * 256 * 4;   // 204,800,000
    const size_t SZH = (size_t)NN * 256 * 2;   // 102,400,000
    float*          R0f = (float*)ws;                         // final h2b f32
    unsigned short* R0h = (unsigned short*)ws;                // h1o bf16 (first half)
    unsigned short* R1  = (unsigned short*)(ws + SZF);
    unsigned short* R2  = (unsigned short*)(ws + SZF + SZH);
    // CSR inside R0 second half:
    char* q = ws + SZH;                        // = ws + 102,400,000 (16-aligned)
    int* deg    = (int*)q; q += (size_t)NN * 4;
    int* rowptr = (int*)q; q += (size_t)(NN + 1) * 4;
    int* cursor = (int*)q; q += (size_t)NN * 4;
    int* srcs   = (int*)q; q += (size_t)NE * 4;
    int* eidx   = (int*)q; q += (size_t)NE * 4;
    int* bsum   = (int*)q;                     // ends well inside R0
    // weights + flag at round-2 offsets:
    char* p = ws + SZF + 2 * SZH;
    unsigned short* Wt1a = (unsigned short*)p; p += 128 * 256 * 2;
    unsigned short* Wt1b = (unsigned short*)p; p += 256 * 256 * 2;
    unsigned short* Wt2a = (unsigned short*)p; p += 256 * 256 * 2;
    unsigned short* Wt2b = (unsigned short*)p; p += 256 * 256 * 2;
    int* flag = (int*)p;

    detect_i64<<<1, 64, 0, stream>>>(ei, flag);
    wt_conv<<<(128 * 256 + 255) / 256, 256, 0, stream>>>(W1a, Wt1a, 128, 256);
    wt_conv<<<(256 * 256 + 255) / 256, 256, 0, stream>>>(W1b, Wt1b, 256, 256);
    wt_conv<<<(256 * 256 + 255) / 256, 256, 0, stream>>>(W2a, Wt2a, 256, 256);
    wt_conv<<<(256 * 256 + 255) / 256, 256, 0, stream>>>(W2b, Wt2b, 256, 256);

    // ---- CSR build (once; shared by both layers) ----
    hipMemsetAsync(deg, 0, (size_t)NN * 4, stream);
    hist_dst<<<(NE + 255) / 256, 256, 0, stream>>>(ei, flag, deg);
    scan_bsum<<<NSCAN, 256, 0, stream>>>(deg, bsum);
    scan_carry<<<1, 64, 0, stream>>>(bsum, rowptr + NN);
    scan_final<<<NSCAN, 256, 0, stream>>>(deg, bsum, rowptr);
    copy_int<<<(NN + 255) / 256, 256, 0, stream>>>(rowptr, cursor, NN);
    fill_csr<<<(NE + 255) / 256, 256, 0, stream>>>(ei, flag, cursor, srcs, eidx);

    dim3 gg(4, 3125);   // 200000/64 = 3125, 256/64 = 4

    // ---- layer 1 ----
    gather_aggr<128, float><<<NN / 4, 256, 0, stream>>>(x, ea, We1, be1, rowptr, srcs, eidx, R1);
    gemm_bias_relu<128, unsigned short><<<gg, 256, 0, stream>>>(R1, Wt1a, b1a, R2);
    gemm_bias_relu<256, unsigned short><<<gg, 256, 0, stream>>>(R2, Wt1b, b1b, R0h);

    // ---- layer 2 ----
    gather_aggr<256, unsigned short><<<NN / 4, 256, 0, stream>>>(R0h, ea, We2, be2, rowptr, srcs, eidx, R1);
    gemm_bias_relu<256, unsigned short><<<gg, 256, 0, stream>>>(R1, Wt2a, b2a, R2);
    gemm_bias_relu<256, float><<<gg, 256, 0, stream>>>(R2, Wt2b, b2b, R0f);  // overwrites dead CSR + h1o

    // ---- mean pool ----
    pool_mean<<<NG, 256, 0, stream>>>(R0f, bat, flag, out);
}